// Round 1
// baseline (40592.902 us; speedup 1.0000x reference)
//
#include <hip/hip_runtime.h>
#include <math.h>

// Problem constants (from reference)
#define T_SEQ   8192
#define N_RES   2048
#define K_IN    512

// Launch geometry
#define G_BLOCKS 128
#define B_THREADS 256            // 4 waves
#define WAVES_PER_BLOCK (B_THREADS / 64)      // 4
#define ROWS_PER_WAVE 4
#define ROWS_PER_BLOCK (WAVES_PER_BLOCK * ROWS_PER_WAVE)  // 16
// G_BLOCKS * ROWS_PER_BLOCK == 2048 == N_RES  (checked below)

static_assert(G_BLOCKS * ROWS_PER_BLOCK == N_RES, "row partition mismatch");

// 1/sqrt(2048)
#define INV_SQRT_N 0.022097086912079612f

__global__ __launch_bounds__(B_THREADS)
void reservoir_persistent(const float* __restrict__ input,   // [T_SEQ][K_IN]
                          const float* __restrict__ state0,  // [N_RES]
                          const float* __restrict__ W_in,    // [N_RES][K_IN]
                          const float* __restrict__ W_res,   // [N_RES][N_RES]
                          float* __restrict__ out,           // [T_SEQ+1][N_RES]
                          unsigned int* __restrict__ bar_cnt)
{
    const int tid  = threadIdx.x;
    const int lane = tid & 63;
    const int wave = tid >> 6;
    const int blk  = blockIdx.x;
    const int row_base = blk * ROWS_PER_BLOCK + wave * ROWS_PER_WAVE;

    // ---- Persistent weights in registers ----
    // W_res row r, lane l holds columns {4l+256*i .. 4l+256*i+3} for i=0..7 (32 cols)
    // W_in  row r, lane l holds columns {4l+256*i .. } for i=0..1 (8 cols)
    float4 wr[ROWS_PER_WAVE][8];
    float4 wi[ROWS_PER_WAVE][2];
    #pragma unroll
    for (int k = 0; k < ROWS_PER_WAVE; ++k) {
        const float* rrow = W_res + (size_t)(row_base + k) * N_RES;
        #pragma unroll
        for (int i = 0; i < 8; ++i)
            wr[k][i] = *reinterpret_cast<const float4*>(rrow + 4 * lane + 256 * i);
        const float* irow = W_in + (size_t)(row_base + k) * K_IN;
        #pragma unroll
        for (int i = 0; i < 2; ++i)
            wi[k][i] = *reinterpret_cast<const float4*>(irow + 4 * lane + 256 * i);
    }

    // Row 0 of the output is the initial state (written once, never read here)
    if (blk == 0) {
        for (int j = tid; j < N_RES; j += B_THREADS) out[j] = state0[j];
    }

    for (unsigned int t = 0; t < T_SEQ; ++t) {
        // ---- load s_t (coalesced: instr i reads 1KB contiguous) ----
        const float* s = (t == 0) ? state0 : (out + (size_t)t * N_RES);
        float4 sv[8];
        #pragma unroll
        for (int i = 0; i < 8; ++i)
            sv[i] = *reinterpret_cast<const float4*>(s + 4 * lane + 256 * i);

        // ---- load x_t slice ----
        const float* xrow = input + (size_t)t * K_IN;
        float4 xv[2];
        #pragma unroll
        for (int i = 0; i < 2; ++i)
            xv[i] = *reinterpret_cast<const float4*>(xrow + 4 * lane + 256 * i);

        // ---- partial dots: W_res[row]·s + W_in[row]·x ----
        float acc[ROWS_PER_WAVE];
        #pragma unroll
        for (int k = 0; k < ROWS_PER_WAVE; ++k) {
            float a = 0.0f;
            #pragma unroll
            for (int i = 0; i < 8; ++i) {
                a = fmaf(wr[k][i].x, sv[i].x, a);
                a = fmaf(wr[k][i].y, sv[i].y, a);
                a = fmaf(wr[k][i].z, sv[i].z, a);
                a = fmaf(wr[k][i].w, sv[i].w, a);
            }
            #pragma unroll
            for (int i = 0; i < 2; ++i) {
                a = fmaf(wi[k][i].x, xv[i].x, a);
                a = fmaf(wi[k][i].y, xv[i].y, a);
                a = fmaf(wi[k][i].z, xv[i].z, a);
                a = fmaf(wi[k][i].w, xv[i].w, a);
            }
            acc[k] = a;
        }

        // ---- full-wave butterfly reduction per row ----
        #pragma unroll
        for (int k = 0; k < ROWS_PER_WAVE; ++k) {
            float a = acc[k];
            #pragma unroll
            for (int off = 32; off > 0; off >>= 1)
                a += __shfl_xor(a, off, 64);
            acc[k] = a;
        }

        // ---- lanes 0..3 finalize their row (static-index select, no scratch) ----
        if (lane < ROWS_PER_WAVE) {
            float v = acc[0];
            v = (lane == 1) ? acc[1] : v;
            v = (lane == 2) ? acc[2] : v;
            v = (lane == 3) ? acc[3] : v;
            // tanh(v) = 1 - 2/(e^{2v}+1); saturates correctly for |v| large
            float e  = __expf(2.0f * v);
            float th = 1.0f - 2.0f / (e + 1.0f);
            out[(size_t)(t + 1) * N_RES + (row_base + lane)] = th * INV_SQRT_N;
        }

        // ---- global barrier: monotonic counter, release/acquire at agent scope ----
        __syncthreads();   // drains vmcnt: all this block's stores are in L2
        if (tid == 0) {
            __builtin_amdgcn_fence(__ATOMIC_RELEASE, "agent");
            __hip_atomic_fetch_add(bar_cnt, 1u, __ATOMIC_RELAXED, __HIP_MEMORY_SCOPE_AGENT);
            const unsigned int target = (t + 1) * (unsigned int)G_BLOCKS;
            while (__hip_atomic_load(bar_cnt, __ATOMIC_RELAXED, __HIP_MEMORY_SCOPE_AGENT) < target) { }
            __builtin_amdgcn_fence(__ATOMIC_ACQUIRE, "agent");
        }
        __syncthreads();
    }
}

extern "C" void kernel_launch(void* const* d_in, const int* in_sizes, int n_in,
                              void* d_out, int out_size, void* d_ws, size_t ws_size,
                              hipStream_t stream) {
    const float* input  = (const float*)d_in[0];
    const float* state0 = (const float*)d_in[1];
    const float* W_in   = (const float*)d_in[2];
    const float* W_res  = (const float*)d_in[3];
    float* out = (float*)d_out;
    unsigned int* bar_cnt = (unsigned int*)d_ws;

    // barrier counter must start at 0 every call (monotonic within a call)
    hipMemsetAsync(d_ws, 0, 64, stream);

    void* args[] = { (void*)&input, (void*)&state0, (void*)&W_in, (void*)&W_res,
                     (void*)&out, (void*)&bar_cnt };
    hipLaunchCooperativeKernel((const void*)reservoir_persistent,
                               dim3(G_BLOCKS), dim3(B_THREADS),
                               args, 0, stream);
}

// Round 2
// 32532.401 us; speedup vs baseline: 1.2478x; 1.2478x over previous
//
#include <hip/hip_runtime.h>

// Problem constants
#define T_SEQ   8192
#define N_RES   2048
#define K_IN    512

// Geometry: 128 blocks x 256 threads (4 waves), 1 block/CU possible -> 512 VGPR budget
#define G_BLOCKS 128
#define B_THREADS 256
#define ROWS_PER_WAVE 4
#define ROWS_PER_BLOCK 16   // 4 waves * 4 rows
static_assert(G_BLOCKS * ROWS_PER_BLOCK == N_RES, "row partition mismatch");

#define INV_SQRT_N 0.022097086912079612f

typedef unsigned long long u64;
typedef unsigned int u32;

// Data-flow sync: state element j of step t is published as an 8-byte packet
//   low 32 = float bits, high 32 = tag (t). Relaxed agent-scope atomics compile
//   to sc1 accesses that bypass L1/L2 (no fences, no cache invalidation), so the
//   register/cache-resident weights are never blown away.
// 2-slot ring (slot = t & 1): safe because writing s_{t+2} implies every block
// finished reading s_t, and a reader spinning for tag t can never observe t+2.

__global__ __launch_bounds__(B_THREADS, 1)
void reservoir_flow(const float* __restrict__ input,   // [T_SEQ][K_IN]
                    const float* __restrict__ state0,  // [N_RES]
                    const float* __restrict__ W_in,    // [N_RES][K_IN]
                    const float* __restrict__ W_res,   // [N_RES][N_RES]
                    float* __restrict__ out,           // [T_SEQ+1][N_RES]
                    u64* __restrict__ tagged)          // [2][N_RES] in d_ws
{
    const int tid  = threadIdx.x;
    const int lane = tid & 63;
    const int wave = tid >> 6;
    const int blk  = blockIdx.x;
    const int row_base = blk * ROWS_PER_BLOCK + wave * ROWS_PER_WAVE;

    __shared__ float s_lds[2][N_RES];   // double-buffered state (16 KB)

    // ---- persistent weights: lane l holds W cols {4l+256i} ----
    float4 wr[ROWS_PER_WAVE][8];
    float4 wi[ROWS_PER_WAVE][2];
    #pragma unroll
    for (int k = 0; k < ROWS_PER_WAVE; ++k) {
        const float* rrow = W_res + (size_t)(row_base + k) * N_RES;
        #pragma unroll
        for (int i = 0; i < 8; ++i)
            wr[k][i] = *reinterpret_cast<const float4*>(rrow + 4 * lane + 256 * i);
        const float* irow = W_in + (size_t)(row_base + k) * K_IN;
        #pragma unroll
        for (int i = 0; i < 2; ++i)
            wi[k][i] = *reinterpret_cast<const float4*>(irow + 4 * lane + 256 * i);
    }
    // Pin weights in VGPRs: opaque asm makes the values non-rematerializable,
    // so the compiler cannot re-load them from memory inside the loop.
    #pragma unroll
    for (int k = 0; k < ROWS_PER_WAVE; ++k) {
        #pragma unroll
        for (int i = 0; i < 8; ++i)
            asm volatile("" : "+v"(wr[k][i].x), "+v"(wr[k][i].y),
                              "+v"(wr[k][i].z), "+v"(wr[k][i].w));
        #pragma unroll
        for (int i = 0; i < 2; ++i)
            asm volatile("" : "+v"(wi[k][i].x), "+v"(wi[k][i].y),
                              "+v"(wi[k][i].z), "+v"(wi[k][i].w));
    }

    // out row 0 = initial state
    if (blk == 0)
        for (int j = tid; j < N_RES; j += B_THREADS) out[j] = state0[j];

    // preload input row 0
    float4 xv[2];
    #pragma unroll
    for (int i = 0; i < 2; ++i)
        xv[i] = *reinterpret_cast<const float4*>(input + 4 * lane + 256 * i);

    // s_0 -> LDS buffer 0 (coalesced: instr i writes stride-1 across threads)
    #pragma unroll
    for (int i = 0; i < 8; ++i)
        s_lds[0][i * 256 + tid] = state0[i * 256 + tid];

    for (int t = 0; t < T_SEQ; ++t) {
        const int buf = t & 1;

        if (t > 0) {
            // ---- spin-load tagged s_t (coalesced: instr i covers 512B contiguous) ----
            u64* tp = tagged + (size_t)buf * N_RES;
            u64 v[8];
            u32 pending = 0xFFu;
            while (pending) {
                #pragma unroll
                for (int i = 0; i < 8; ++i) {
                    if (pending & (1u << i)) {
                        u64 e = __hip_atomic_load(tp + i * 256 + tid,
                                                  __ATOMIC_RELAXED, __HIP_MEMORY_SCOPE_AGENT);
                        if ((u32)(e >> 32) == (u32)t) { v[i] = e; pending &= ~(1u << i); }
                    }
                }
            }
            #pragma unroll
            for (int i = 0; i < 8; ++i)
                s_lds[buf][i * 256 + tid] = __uint_as_float((u32)v[i]);
        }
        __syncthreads();

        // prefetch next input row; latency hides under compute + next spin
        float4 xn[2];
        if (t + 1 < T_SEQ) {
            const float* xrow = input + (size_t)(t + 1) * K_IN;
            #pragma unroll
            for (int i = 0; i < 2; ++i)
                xn[i] = *reinterpret_cast<const float4*>(xrow + 4 * lane + 256 * i);
        } else {
            #pragma unroll
            for (int i = 0; i < 2; ++i) xn[i] = xv[i];
        }

        // state fragment for this lane (uniform 8 words/bank -> near-optimal)
        float4 sv[8];
        #pragma unroll
        for (int i = 0; i < 8; ++i)
            sv[i] = *reinterpret_cast<const float4*>(&s_lds[buf][4 * lane + 256 * i]);

        // partial dots
        float acc[ROWS_PER_WAVE];
        #pragma unroll
        for (int k = 0; k < ROWS_PER_WAVE; ++k) {
            float a = 0.0f;
            #pragma unroll
            for (int i = 0; i < 8; ++i) {
                a = fmaf(wr[k][i].x, sv[i].x, a);
                a = fmaf(wr[k][i].y, sv[i].y, a);
                a = fmaf(wr[k][i].z, sv[i].z, a);
                a = fmaf(wr[k][i].w, sv[i].w, a);
            }
            #pragma unroll
            for (int i = 0; i < 2; ++i) {
                a = fmaf(wi[k][i].x, xv[i].x, a);
                a = fmaf(wi[k][i].y, xv[i].y, a);
                a = fmaf(wi[k][i].z, xv[i].z, a);
                a = fmaf(wi[k][i].w, xv[i].w, a);
            }
            acc[k] = a;
        }

        // full-wave butterfly reduce, 4 rows in flight
        #pragma unroll
        for (int k = 0; k < ROWS_PER_WAVE; ++k) {
            float a = acc[k];
            #pragma unroll
            for (int off = 32; off > 0; off >>= 1)
                a += __shfl_xor(a, off, 64);
            acc[k] = a;
        }

        // lanes 0..3 publish their row
        if (lane < ROWS_PER_WAVE) {
            float v = acc[0];
            v = (lane == 1) ? acc[1] : v;
            v = (lane == 2) ? acc[2] : v;
            v = (lane == 3) ? acc[3] : v;
            float e   = __expf(2.0f * v);
            float res = (1.0f - 2.0f / (e + 1.0f)) * INV_SQRT_N;
            const int row = row_base + lane;
            u64 pk = (u64)__float_as_uint(res) | ((u64)(u32)(t + 1) << 32);
            __hip_atomic_store(&tagged[(size_t)((t + 1) & 1) * N_RES + row], pk,
                               __ATOMIC_RELAXED, __HIP_MEMORY_SCOPE_AGENT);
            out[(size_t)(t + 1) * N_RES + row] = res;
        }

        #pragma unroll
        for (int i = 0; i < 2; ++i) xv[i] = xn[i];
    }
}

extern "C" void kernel_launch(void* const* d_in, const int* in_sizes, int n_in,
                              void* d_out, int out_size, void* d_ws, size_t ws_size,
                              hipStream_t stream) {
    const float* input  = (const float*)d_in[0];
    const float* state0 = (const float*)d_in[1];
    const float* W_in   = (const float*)d_in[2];
    const float* W_res  = (const float*)d_in[3];
    float* out = (float*)d_out;
    u64* tagged = (u64*)d_ws;

    // clear tags every call (expected tags are >= 1, so zero never matches)
    hipMemsetAsync(d_ws, 0, 2 * N_RES * sizeof(u64), stream);

    void* args[] = { (void*)&input, (void*)&state0, (void*)&W_in, (void*)&W_res,
                     (void*)&out, (void*)&tagged };
    hipLaunchCooperativeKernel((const void*)reservoir_flow,
                               dim3(G_BLOCKS), dim3(B_THREADS),
                               args, 0, stream);
}